// Round 14
// baseline (135.597 us; speedup 1.0000x reference)
//
#include <hip/hip_runtime.h>
#include <hip/hip_fp16.h>

// GCN 2-layer forward — f16 CSR-gather with SEQUENTIAL FEATURE-SLICE passes.
//  k_histbin: per-tile hist over 196 buckets + LDS scan -> tileOff; scatter
//             reg-held edges to tile-major binned runs.
//  k_csr:     per-bucket counting sort (self-contained base) -> rowPtr/dinv/
//             eSrc; fused prescale writes 4 slice tables Xt[p][node][16] f16.
//  k_agg_slice x4 (one launch per slice p): whole GPU gathers from ONE 3.2MB
//             slice -> resident in every XCD L2. aggT[p][node][16] = f16 rows.
//  k_mlp:     16x16x32_f16 MFMA, A-frags from slice tables ->
//             svs = dinv * dot(relu(agg@W1+b1), W2).
//  k_out:     scalar CSR gather: out = dD*(sum svs[src]+svs[d]) + b2.

#define INF 64
#define HID 128
#define BKBITS 9
#define BKSZ 512      // nodes per bucket
#define TILE_E 8192   // edges per tile (1024 thr x 8)
#define TOW 257       // tileOff row width

using half8 = __attribute__((ext_vector_type(8))) _Float16;
using f32x4 = __attribute__((ext_vector_type(4))) float;

// Per-tile histogram + in-LDS scan + scatter. Extra block (bx==nt): W1t prep.
__global__ __launch_bounds__(1024) void k_histbin(const int* __restrict__ srcA,
                                                  const int* __restrict__ dstA,
                                                  int* __restrict__ tileOff,
                                                  unsigned* __restrict__ binned,
                                                  int nE, int nt,
                                                  const float* __restrict__ W1,
                                                  _Float16* __restrict__ W1t) {
    int tid = threadIdx.x;
    int bx = blockIdx.x;
    if (bx == nt) {  // W1t[n][k] = f16(W1[k][n])
        for (int i = tid; i < HID * INF; i += 1024) {
            int nCol = i >> 6;
            int k = i & 63;
            W1t[i] = (_Float16)W1[k * HID + nCol];
        }
        return;
    }
    __shared__ int hist[256];
    __shared__ int curs[256];
    if (tid < 256) hist[tid] = 0;
    __syncthreads();
    int base = bx * TILE_E;
    int d[8], s[8];
#pragma unroll
    for (int k = 0; k < 8; ++k) {
        int e = base + k * 1024 + tid;
        if (e < nE) {
            d[k] = dstA[e];
            s[k] = srcA[e];
            atomicAdd(&hist[((unsigned)d[k]) >> BKBITS], 1);
        } else {
            d[k] = -1;
        }
    }
    __syncthreads();
    int own = (tid < 256) ? hist[tid] : 0;
    for (int off = 1; off < 256; off <<= 1) {
        int u = (tid < 256 && tid >= off) ? hist[tid - off] : 0;
        __syncthreads();
        if (tid < 256) hist[tid] += u;
        __syncthreads();
    }
    if (tid < 256) {
        int ex = hist[tid] - own;
        curs[tid] = ex;
        tileOff[bx * TOW + tid] = ex;
        if (tid == 255) tileOff[bx * TOW + 256] = hist[255];
    }
    __syncthreads();
#pragma unroll
    for (int k = 0; k < 8; ++k) {
        if (d[k] >= 0) {
            int bk = ((unsigned)d[k]) >> BKBITS;
            int off = atomicAdd(&curs[bk], 1);
            binned[base + off] = ((unsigned)(d[k] & (BKSZ - 1)) << 17) | (unsigned)s[k];
        }
    }
}

// Per-bucket counting sort + fused prescale into 4 slice tables.
__global__ __launch_bounds__(1024) void k_csr(const unsigned* __restrict__ binned,
                                              const int* __restrict__ tileOff,
                                              int* __restrict__ rowPtr,
                                              float* __restrict__ dinv,
                                              int* __restrict__ eSrc,
                                              const float4* __restrict__ X4,
                                              uint4* __restrict__ Xt,
                                              int n, int nt, int nbk) {
    __shared__ int segS[256], segL[256];
    __shared__ int hist[512];
    __shared__ int curs[512];
    __shared__ float ddv[512];
    __shared__ int bBaseS;
    int tid = threadIdx.x;
    int b = blockIdx.x;
    if (tid == 0) bBaseS = 0;
    if (tid < 512) hist[tid] = 0;
    __syncthreads();
    if (tid < nt) {
        int o0 = tileOff[tid * TOW + b];
        int o1 = tileOff[tid * TOW + b + 1];
        segS[tid] = tid * TILE_E + o0;
        segL[tid] = o1 - o0;
        atomicAdd(&bBaseS, o0);
    }
    __syncthreads();
    int w = tid >> 6, lane = tid & 63;
    for (int t = w; t < nt; t += 16)
        for (int l = lane; l < segL[t]; l += 64)
            atomicAdd(&hist[binned[segS[t] + l] >> 17], 1);
    __syncthreads();
    int own = (tid < 512) ? hist[tid] : 0;
    for (int off = 1; off < 512; off <<= 1) {
        int u = (tid < 512 && tid >= off) ? hist[tid - off] : 0;
        __syncthreads();
        if (tid < 512) hist[tid] += u;
        __syncthreads();
    }
    int bBase = bBaseS;
    if (tid < 512) {
        int pos0 = bBase + hist[tid] - own;
        curs[tid] = pos0;
        float dD = rsqrtf((float)(own + 1));  // +1 self loop
        ddv[tid] = dD;
        int node = (b << BKBITS) + tid;
        if (node < n) {
            rowPtr[node] = pos0;
            dinv[node] = dD;
        }
        if (b == nbk - 1 && tid == 511) rowPtr[n] = bBase + hist[511];
    }
    __syncthreads();
    for (int t = w; t < nt; t += 16)
        for (int l = lane; l < segL[t]; l += 64) {
            unsigned v = binned[segS[t] + l];
            int pos = atomicAdd(&curs[v >> 17], 1);
            eSrc[pos] = (int)(v & 0x1FFFFu);
        }
    // fused prescale into slice tables: Xt[p][node][16] (p = r2>>1, c = r2&1)
    int nbase = b << BKBITS;
#pragma unroll
    for (int k2 = 0; k2 < 4; ++k2) {
        int t2 = k2 * 1024 + tid;
        int nl = t2 >> 3;
        int r2 = t2 & 7;
        int node2 = nbase + nl;
        if (node2 < n) {
            float dD2 = ddv[nl];
            float4 a = X4[(size_t)node2 * 16 + r2 * 2];
            float4 bb = X4[(size_t)node2 * 16 + r2 * 2 + 1];
            __half2 h0 = __float22half2_rn(make_float2(dD2 * a.x, dD2 * a.y));
            __half2 h1 = __float22half2_rn(make_float2(dD2 * a.z, dD2 * a.w));
            __half2 h2 = __float22half2_rn(make_float2(dD2 * bb.x, dD2 * bb.y));
            __half2 h3 = __float22half2_rn(make_float2(dD2 * bb.z, dD2 * bb.w));
            uint4 o;
            o.x = *(unsigned*)&h0; o.y = *(unsigned*)&h1;
            o.z = *(unsigned*)&h2; o.w = *(unsigned*)&h3;
            Xt[(size_t)(r2 >> 1) * n * 2 + (size_t)node2 * 2 + (r2 & 1)] = o;
        }
    }
}

__device__ inline void acc8_set(const uint4& v, float* acc) {
    const __half2* hp = (const __half2*)&v;
#pragma unroll
    for (int i = 0; i < 4; ++i) {
        float2 f = __half22float2(hp[i]);
        acc[2 * i] = f.x;
        acc[2 * i + 1] = f.y;
    }
}
__device__ inline void acc8_add(const uint4& v, float* acc) {
    const __half2* hp = (const __half2*)&v;
#pragma unroll
    for (int i = 0; i < 4; ++i) {
        float2 f = __half22float2(hp[i]);
        acc[2 * i]     += f.x;
        acc[2 * i + 1] += f.y;
    }
}

// One slice pass: thread = (node, 16B chunk c). Gathers 32B/edge from the
// L2-resident 3.2MB slice table; aggT[p][node] = f16(dD * sum).
__global__ __launch_bounds__(256) void k_agg_slice(const uint4* __restrict__ Xt,
                                                   const int* __restrict__ rowPtr,
                                                   const int* __restrict__ eSrc,
                                                   const float* __restrict__ dinv,
                                                   uint4* __restrict__ aggT,
                                                   int n, int p) {
    int gid = blockIdx.x * 256 + threadIdx.x;
    int node = gid >> 1;
    int c = gid & 1;
    if (node >= n) return;
    const uint4* tab = Xt + (size_t)p * n * 2;
    int beg = rowPtr[node];
    int end = rowPtr[node + 1];
    float dD = dinv[node];
    float acc[8];
    acc8_set(tab[(size_t)node * 2 + c], acc);  // self loop
    int j = beg;
    int aEnd = min(end, (beg + 3) & ~3);
    for (; j < aEnd; ++j) acc8_add(tab[(size_t)eSrc[j] * 2 + c], acc);
    for (; j + 7 < end; j += 8) {
        int4 sa = *(const int4*)(eSrc + j);
        int4 sb = *(const int4*)(eSrc + j + 4);
        uint4 v0 = tab[(size_t)sa.x * 2 + c];
        uint4 v1 = tab[(size_t)sa.y * 2 + c];
        uint4 v2 = tab[(size_t)sa.z * 2 + c];
        uint4 v3 = tab[(size_t)sa.w * 2 + c];
        uint4 v4 = tab[(size_t)sb.x * 2 + c];
        uint4 v5 = tab[(size_t)sb.y * 2 + c];
        uint4 v6 = tab[(size_t)sb.z * 2 + c];
        uint4 v7 = tab[(size_t)sb.w * 2 + c];
        acc8_add(v0, acc); acc8_add(v1, acc); acc8_add(v2, acc); acc8_add(v3, acc);
        acc8_add(v4, acc); acc8_add(v5, acc); acc8_add(v6, acc); acc8_add(v7, acc);
    }
    if (j + 3 < end) {
        int4 s4 = *(const int4*)(eSrc + j);
        uint4 v0 = tab[(size_t)s4.x * 2 + c];
        uint4 v1 = tab[(size_t)s4.y * 2 + c];
        uint4 v2 = tab[(size_t)s4.z * 2 + c];
        uint4 v3 = tab[(size_t)s4.w * 2 + c];
        acc8_add(v0, acc); acc8_add(v1, acc); acc8_add(v2, acc); acc8_add(v3, acc);
        j += 4;
    }
    for (; j < end; ++j) acc8_add(tab[(size_t)eSrc[j] * 2 + c], acc);
    __half2 h0 = __float22half2_rn(make_float2(dD * acc[0], dD * acc[1]));
    __half2 h1 = __float22half2_rn(make_float2(dD * acc[2], dD * acc[3]));
    __half2 h2 = __float22half2_rn(make_float2(dD * acc[4], dD * acc[5]));
    __half2 h3 = __float22half2_rn(make_float2(dD * acc[6], dD * acc[7]));
    uint4 o;
    o.x = *(unsigned*)&h0; o.y = *(unsigned*)&h1;
    o.z = *(unsigned*)&h2; o.w = *(unsigned*)&h3;
    aggT[(size_t)p * n * 2 + (size_t)node * 2 + c] = o;
}

// MFMA MLP: wave per 16-node tile; A-frags from slice tables.
// svs[m] = dinv[m] * sum_col relu(agg[m]@W1 + b1)[col] * W2[col]
__global__ __launch_bounds__(256) void k_mlp(const uint4* __restrict__ aggT,
                                             const uint4* __restrict__ W1t4,
                                             const float* __restrict__ b1,
                                             const float* __restrict__ W2,
                                             const float* __restrict__ dinv,
                                             float* __restrict__ svs,
                                             int nTiles, int n) {
    int lane = threadIdx.x & 63;
    int tile = (blockIdx.x * blockDim.x + threadIdx.x) >> 6;
    if (tile >= nTiles) return;
    int m0 = tile * 16;
    int row = lane & 15;   // A row / B col
    int kg = lane >> 4;    // k-group (8 halfs each)

    half8 bf[8][2];
    float b1v[8], w2v[8];
#pragma unroll
    for (int nt = 0; nt < 8; ++nt) {
        int col = nt * 16 + row;
#pragma unroll
        for (int ks = 0; ks < 2; ++ks) {
            uint4 u = W1t4[col * 8 + ks * 4 + kg];
            bf[nt][ks] = __builtin_bit_cast(half8, u);
        }
        b1v[nt] = b1[col];
        w2v[nt] = W2[col];
    }

    int node = m0 + row;
    // a0: feats kg*8..+8 -> slice kg>>1, chunk kg&1 ; a1: feats 32+kg*8
    uint4 ua0 = aggT[(size_t)(kg >> 1) * n * 2 + (size_t)node * 2 + (kg & 1)];
    uint4 ua1 = aggT[(size_t)(2 + (kg >> 1)) * n * 2 + (size_t)node * 2 + (kg & 1)];
    half8 a0 = __builtin_bit_cast(half8, ua0);
    half8 a1 = __builtin_bit_cast(half8, ua1);

    float p0 = 0.0f, p1 = 0.0f, p2 = 0.0f, p3 = 0.0f;
#pragma unroll
    for (int nt = 0; nt < 8; ++nt) {
        f32x4 acc = {0.0f, 0.0f, 0.0f, 0.0f};
        acc = __builtin_amdgcn_mfma_f32_16x16x32_f16(a0, bf[nt][0], acc, 0, 0, 0);
        acc = __builtin_amdgcn_mfma_f32_16x16x32_f16(a1, bf[nt][1], acc, 0, 0, 0);
        float h;
        h = fmaxf(acc[0] + b1v[nt], 0.0f); p0 = fmaf(h, w2v[nt], p0);
        h = fmaxf(acc[1] + b1v[nt], 0.0f); p1 = fmaf(h, w2v[nt], p1);
        h = fmaxf(acc[2] + b1v[nt], 0.0f); p2 = fmaf(h, w2v[nt], p2);
        h = fmaxf(acc[3] + b1v[nt], 0.0f); p3 = fmaf(h, w2v[nt], p3);
    }
#pragma unroll
    for (int off = 1; off < 16; off <<= 1) {
        p0 += __shfl_xor(p0, off, 64);
        p1 += __shfl_xor(p1, off, 64);
        p2 += __shfl_xor(p2, off, 64);
        p3 += __shfl_xor(p3, off, 64);
    }
    if (row == 0) {
        int nd = m0 + kg * 4;
        if (nd + 0 < n) svs[nd + 0] = dinv[nd + 0] * p0;
        if (nd + 1 < n) svs[nd + 1] = dinv[nd + 1] * p1;
        if (nd + 2 < n) svs[nd + 2] = dinv[nd + 2] * p2;
        if (nd + 3 < n) svs[nd + 3] = dinv[nd + 3] * p3;
    }
}

// 4 nodes per wave: out[d] = dD*(sum svs[src] + svs[d]) + b2
__global__ __launch_bounds__(256) void k_out(const int* __restrict__ rowPtr,
                                             const int* __restrict__ eSrc,
                                             const float* __restrict__ dinv,
                                             const float* __restrict__ svs,
                                             const float* __restrict__ b2,
                                             float* __restrict__ out, int n) {
    int t = blockIdx.x * blockDim.x + threadIdx.x;
    int node = t >> 4;
    int r = t & 15;
    if (node >= n) return;
    int beg = rowPtr[node];
    int end = rowPtr[node + 1];
    float p = 0.0f;
    for (int j = beg + r; j < end; j += 16) p += svs[eSrc[j]];
    p += __shfl_xor(p, 1, 16);
    p += __shfl_xor(p, 2, 16);
    p += __shfl_xor(p, 4, 16);
    p += __shfl_xor(p, 8, 16);
    if (r == 0) {
        float dD = dinv[node];
        out[node] = fmaf(dD, p + svs[node], b2[0]);
    }
}

extern "C" void kernel_launch(void* const* d_in, const int* in_sizes, int n_in,
                              void* d_out, int out_size, void* d_ws, size_t ws_size,
                              hipStream_t stream) {
    const float* X  = (const float*)d_in[0];
    const int*   ei = (const int*)d_in[1];   // int32 (jax x64 disabled)
    const float* W1 = (const float*)d_in[2];
    const float* b1 = (const float*)d_in[3];
    const float* W2 = (const float*)d_in[4];
    const float* b2 = (const float*)d_in[5];

    int N = in_sizes[0] / INF;  // 100000
    int E = in_sizes[1] / 2;    // 1600000
    const int* srcA = ei;
    const int* dstA = ei + E;

    int nt  = (E + TILE_E - 1) / TILE_E;       // 196 tiles
    int nbk = (N + BKSZ - 1) >> BKBITS;        // 196 buckets

    // workspace layout (16B-aligned head first)
    uint4*    Xt       = (uint4*)d_ws;                     // 4 slices: N*8 u4
    uint4*    aggT     = Xt + (size_t)N * 8;               // 4 slices: N*8 u4
    unsigned* binned   = (unsigned*)(aggT + (size_t)N * 8);// nt*TILE_E
    int*      eSrc     = (int*)(binned + (size_t)nt * TILE_E);  // E
    _Float16* W1t      = (_Float16*)(eSrc + E);            // HID*INF
    int*      tileOff  = (int*)(W1t + HID * INF);          // nt*TOW
    int*      rowPtr   = tileOff + nt * TOW;               // N+1
    float*    dinv     = (float*)(rowPtr + N + 1);         // N
    float*    svs      = dinv + N;                         // N
    float*    out      = (float*)d_out;

    int nTiles = (N + 15) / 16;  // 6250

    k_histbin<<<nt + 1, 1024, 0, stream>>>(srcA, dstA, tileOff, binned, E, nt, W1, W1t);
    k_csr<<<nbk, 1024, 0, stream>>>(binned, tileOff, rowPtr, dinv, eSrc,
                                    (const float4*)X, Xt, N, nt, nbk);
    for (int p = 0; p < 4; ++p)
        k_agg_slice<<<(N * 2 + 255) / 256, 256, 0, stream>>>(Xt, rowPtr, eSrc,
                                                             dinv, aggT, N, p);
    k_mlp<<<(nTiles * 64 + 255) / 256, 256, 0, stream>>>(aggT, (const uint4*)W1t,
                                                         b1, W2, dinv, svs, nTiles, N);
    k_out<<<(N * 16 + 255) / 256, 256, 0, stream>>>(rowPtr, eSrc, dinv, svs, b2, out, N);
}

// Round 15
// 94.245 us; speedup vs baseline: 1.4388x; 1.4388x over previous
//
#include <hip/hip_runtime.h>
#include <hip/hip_fp16.h>

// GCN 2-layer forward — f16 CSR-gather fused with MFMA MLP. 4 launches.
//  k_histbin (262 tiles of 6144 edges): LDS hist over 391 buckets (256 nodes),
//     shfl-scan (2 barriers) -> tileOff; scatter reg-held edges -> binned.
//  k_csr (391 buckets, 512 thr): segments staged to LDS during hist pass,
//     shfl-scans, counting sort -> rowPtr/dinv/eSrc; fused prescale
//     Xs = f16(dinv*X) of own 256 nodes.
//  k_agg_mlp: 32 nodes/block gather (8 rows in flight) -> swizzled LDS ->
//     16x16x32_f16 MFMA MLP -> svs = dinv*dot(relu(agg@W1+b1),W2).
//  k_out: scalar CSR gather: out = dD*(sum svs[src]+svs[d]) + b2.

#define INF 64
#define HID 128
#define BKBITS 8
#define BKSZ 256      // nodes per bucket
#define TILE_E 6144   // edges per tile (1024 thr x 6)
#define EPT 6
#define SEGMAX 384    // max tiles supported by k_csr LDS arrays
#define CAP 5120      // k_csr LDS record capacity (mean ~4092, sigma ~64)

using half8 = __attribute__((ext_vector_type(8))) _Float16;
using f32x4 = __attribute__((ext_vector_type(4))) float;

// Per-tile histogram + shfl scan + scatter. Extra block (bx==nt): W1t prep.
__global__ __launch_bounds__(1024) void k_histbin(const int* __restrict__ srcA,
                                                  const int* __restrict__ dstA,
                                                  int* __restrict__ tileOff,
                                                  unsigned* __restrict__ binned,
                                                  int nE, int nt, int nbk,
                                                  const float* __restrict__ W1,
                                                  _Float16* __restrict__ W1t) {
    int tid = threadIdx.x;
    int bx = blockIdx.x;
    if (bx == nt) {  // W1t[n][k] = f16(W1[k][n])
        for (int i = tid; i < HID * INF; i += 1024) {
            int nCol = i >> 6;
            int k = i & 63;
            W1t[i] = (_Float16)W1[k * HID + nCol];
        }
        return;
    }
    __shared__ int hist[512];
    __shared__ int curs[512];
    __shared__ int wsum[8];
    if (tid < 512) hist[tid] = 0;
    __syncthreads();
    int base = bx * TILE_E;
    int d[EPT], s[EPT];
#pragma unroll
    for (int k = 0; k < EPT; ++k) {
        int e = base + k * 1024 + tid;
        if (e < nE) {
            d[k] = dstA[e];
            s[k] = srcA[e];
            atomicAdd(&hist[((unsigned)d[k]) >> BKBITS], 1);
        } else {
            d[k] = -1;
        }
    }
    __syncthreads();
    int lane = tid & 63, wv = tid >> 6;
    int v = 0, own = 0;
    if (tid < 512) {
        v = hist[tid];
        own = v;
#pragma unroll
        for (int off = 1; off < 64; off <<= 1) {
            int u = __shfl_up(v, off, 64);
            if (lane >= off) v += u;
        }
        if (lane == 63) wsum[wv] = v;
    }
    __syncthreads();
    if (tid < 512) {
        for (int g = 0; g < wv; ++g) v += wsum[g];
        int ex = v - own;
        curs[tid] = ex;
        if (tid <= nbk) tileOff[bx * (nbk + 1) + tid] = ex;
    }
    __syncthreads();
#pragma unroll
    for (int k = 0; k < EPT; ++k) {
        if (d[k] >= 0) {
            int bk = ((unsigned)d[k]) >> BKBITS;
            int off = atomicAdd(&curs[bk], 1);
            binned[base + off] = ((unsigned)(d[k] & (BKSZ - 1)) << 17) | (unsigned)s[k];
        }
    }
}

// Per-bucket counting sort (records staged in LDS) + fused prescale.
__global__ __launch_bounds__(512) void k_csr(const unsigned* __restrict__ binned,
                                             const int* __restrict__ tileOff,
                                             int* __restrict__ rowPtr,
                                             float* __restrict__ dinv,
                                             int* __restrict__ eSrc,
                                             const float4* __restrict__ X4,
                                             uint4* __restrict__ Xs4,
                                             int n, int nt, int nbk) {
    __shared__ int segG[SEGMAX], segL[SEGMAX], segO[SEGMAX];
    __shared__ int hist[BKSZ], curs[BKSZ];
    __shared__ float ddv[BKSZ];
    __shared__ unsigned ldsRec[CAP];  // 20 KB
    __shared__ int wsum[8];
    __shared__ int bBaseS;
    int tid = threadIdx.x;
    int b = blockIdx.x;
    if (tid == 0) bBaseS = 0;
    if (tid < BKSZ) hist[tid] = 0;
    __syncthreads();
    for (int t = tid; t < nt; t += 512) {
        int o0 = tileOff[t * (nbk + 1) + b];
        int o1 = tileOff[t * (nbk + 1) + b + 1];
        segG[t] = t * TILE_E + o0;
        segL[t] = o1 - o0;
        atomicAdd(&bBaseS, o0);  // sum of per-tile excl prefixes = global base
    }
    __syncthreads();
    // shfl scan of segL -> segO (exclusive)
    int lane = tid & 63, wv = tid >> 6;
    int v = (tid < nt) ? segL[tid] : 0;
    int own = v;
#pragma unroll
    for (int off = 1; off < 64; off <<= 1) {
        int u = __shfl_up(v, off, 64);
        if (lane >= off) v += u;
    }
    if (lane == 63) wsum[wv] = v;
    __syncthreads();
    for (int g = 0; g < wv; ++g) v += wsum[g];
    if (tid < nt) segO[tid] = v - own;
    __syncthreads();
    // stage records into LDS + histogram (one global pass)
    int g16 = tid >> 4, l16 = tid & 15;  // 32 groups of 16 lanes
    for (int t = g16; t < nt; t += 32) {
        int L = segL[t], G = segG[t], O = segO[t];
        for (int l = l16; l < L; l += 16) {
            unsigned u = binned[G + l];
            int idx = O + l;
            if (idx < CAP) ldsRec[idx] = u;
            atomicAdd(&hist[u >> 17], 1);
        }
    }
    __syncthreads();
    // shfl scan of hist (256)
    int v2 = (tid < BKSZ) ? hist[tid] : 0;
    int own2 = v2;
#pragma unroll
    for (int off = 1; off < 64; off <<= 1) {
        int u = __shfl_up(v2, off, 64);
        if (lane >= off) v2 += u;
    }
    if (lane == 63) wsum[wv] = v2;
    __syncthreads();
    for (int g = 0; g < wv; ++g) v2 += wsum[g];
    int bBase = bBaseS;
    if (tid < BKSZ) {
        int pos0 = bBase + v2 - own2;
        curs[tid] = pos0;
        float dD = rsqrtf((float)(own2 + 1));  // +1 self loop
        ddv[tid] = dD;
        int node = (b << BKBITS) + tid;
        if (node < n) {
            rowPtr[node] = pos0;
            dinv[node] = dD;
        }
        if (b == nbk - 1 && tid == BKSZ - 1) rowPtr[n] = bBase + v2;
    }
    __syncthreads();
    // scatter
    for (int t = g16; t < nt; t += 32) {
        int L = segL[t], G = segG[t], O = segO[t];
        for (int l = l16; l < L; l += 16) {
            int idx = O + l;
            unsigned u = (idx < CAP) ? ldsRec[idx] : binned[G + l];
            int pos = atomicAdd(&curs[u >> 17], 1);
            eSrc[pos] = (int)(u & 0x1FFFFu);
        }
    }
    // fused prescale of this bucket's nodes (ddv synced by earlier barrier)
    int nbase = b << BKBITS;
    for (int t2 = tid; t2 < BKSZ * 8; t2 += 512) {
        int nl = t2 >> 3;
        int r2 = t2 & 7;
        int node2 = nbase + nl;
        if (node2 < n) {
            float dD2 = ddv[nl];
            float4 a = X4[(size_t)node2 * 16 + r2 * 2];
            float4 bb = X4[(size_t)node2 * 16 + r2 * 2 + 1];
            __half2 h0 = __float22half2_rn(make_float2(dD2 * a.x, dD2 * a.y));
            __half2 h1 = __float22half2_rn(make_float2(dD2 * a.z, dD2 * a.w));
            __half2 h2 = __float22half2_rn(make_float2(dD2 * bb.x, dD2 * bb.y));
            __half2 h3 = __float22half2_rn(make_float2(dD2 * bb.z, dD2 * bb.w));
            uint4 o;
            o.x = *(unsigned*)&h0; o.y = *(unsigned*)&h1;
            o.z = *(unsigned*)&h2; o.w = *(unsigned*)&h3;
            Xs4[(size_t)node2 * 8 + r2] = o;
        }
    }
}

__device__ inline void acc8_add(const uint4& v, float* acc) {
    const __half2* hp = (const __half2*)&v;
#pragma unroll
    for (int i = 0; i < 4; ++i) {
        float2 f = __half22float2(hp[i]);
        acc[2 * i]     += f.x;
        acc[2 * i + 1] += f.y;
    }
}

// Fused gather + MFMA MLP. 256 thr = 32 nodes/block. (R13-proven)
__global__ __launch_bounds__(256) void k_agg_mlp(const uint4* __restrict__ Xs4,
                                                 const int* __restrict__ rowPtr,
                                                 const int* __restrict__ eSrc,
                                                 const float* __restrict__ dinv,
                                                 const uint4* __restrict__ W1t4,
                                                 const float* __restrict__ b1,
                                                 const float* __restrict__ W2,
                                                 float* __restrict__ svs, int n) {
    __shared__ __align__(16) unsigned short W1s[HID * INF];  // 16 KB swizzled
    __shared__ __align__(16) unsigned short aggS[32 * INF];  // 4 KB swizzled
    __shared__ float b1s[HID];
    __shared__ float W2s[HID];
    int tid = threadIdx.x;

    for (int i = tid; i < HID * 8; i += 256) {   // stage W1t swizzled
        int c = i >> 3, cb = i & 7;
        uint4 v = W1t4[i];
        int off = c * 128 + ((cb * 16) ^ ((c & 7) << 4));
        *(uint4*)((char*)W1s + off) = v;
    }
    if (tid < HID) {
        b1s[tid] = b1[tid];
        W2s[tid] = W2[tid];
    }

    int node0 = blockIdx.x * 32;
    int w = tid >> 3;
    int r = tid & 7;
    int node = node0 + w;
    if (node < n) {
        int beg = rowPtr[node];
        int end = rowPtr[node + 1];
        float dD = dinv[node];
        float acc[8];
        {
            uint4 v = Xs4[(size_t)node * 8 + r];
            const __half2* hp = (const __half2*)&v;
#pragma unroll
            for (int i = 0; i < 4; ++i) {
                float2 f = __half22float2(hp[i]);
                acc[2 * i] = f.x;
                acc[2 * i + 1] = f.y;
            }
        }
        int j = beg;
        int aEnd = min(end, (beg + 3) & ~3);
        for (; j < aEnd; ++j) {
            uint4 v = Xs4[(size_t)eSrc[j] * 8 + r];
            acc8_add(v, acc);
        }
        for (; j + 7 < end; j += 8) {
            int4 sa = *(const int4*)(eSrc + j);
            int4 sb = *(const int4*)(eSrc + j + 4);
            uint4 v0 = Xs4[(size_t)sa.x * 8 + r];
            uint4 v1 = Xs4[(size_t)sa.y * 8 + r];
            uint4 v2 = Xs4[(size_t)sa.z * 8 + r];
            uint4 v3 = Xs4[(size_t)sa.w * 8 + r];
            uint4 v4 = Xs4[(size_t)sb.x * 8 + r];
            uint4 v5 = Xs4[(size_t)sb.y * 8 + r];
            uint4 v6 = Xs4[(size_t)sb.z * 8 + r];
            uint4 v7 = Xs4[(size_t)sb.w * 8 + r];
            acc8_add(v0, acc); acc8_add(v1, acc); acc8_add(v2, acc); acc8_add(v3, acc);
            acc8_add(v4, acc); acc8_add(v5, acc); acc8_add(v6, acc); acc8_add(v7, acc);
        }
        if (j + 3 < end) {
            int4 s4 = *(const int4*)(eSrc + j);
            uint4 v0 = Xs4[(size_t)s4.x * 8 + r];
            uint4 v1 = Xs4[(size_t)s4.y * 8 + r];
            uint4 v2 = Xs4[(size_t)s4.z * 8 + r];
            uint4 v3 = Xs4[(size_t)s4.w * 8 + r];
            acc8_add(v0, acc); acc8_add(v1, acc); acc8_add(v2, acc); acc8_add(v3, acc);
            j += 4;
        }
        for (; j < end; ++j) {
            uint4 v = Xs4[(size_t)eSrc[j] * 8 + r];
            acc8_add(v, acc);
        }
        __half2 h0 = __float22half2_rn(make_float2(dD * acc[0], dD * acc[1]));
        __half2 h1 = __float22half2_rn(make_float2(dD * acc[2], dD * acc[3]));
        __half2 h2 = __float22half2_rn(make_float2(dD * acc[4], dD * acc[5]));
        __half2 h3 = __float22half2_rn(make_float2(dD * acc[6], dD * acc[7]));
        uint4 o;
        o.x = *(unsigned*)&h0; o.y = *(unsigned*)&h1;
        o.z = *(unsigned*)&h2; o.w = *(unsigned*)&h3;
        int off = w * 128 + ((r * 16) ^ ((w & 7) << 4));
        *(uint4*)((char*)aggS + off) = o;
    }
    __syncthreads();

    int wave = tid >> 6;
    if (wave < 2) {
        int l = tid & 63;
        int row16 = l & 15;
        int kg = l >> 4;
        int lrow = wave * 16 + row16;
        int swzA = (lrow & 7) << 4;
        half8 a0 = *(const half8*)((const char*)aggS + lrow * 128 + ((kg * 16) ^ swzA));
        half8 a1 = *(const half8*)((const char*)aggS + lrow * 128 + ((64 + kg * 16) ^ swzA));
        float p0 = 0.0f, p1 = 0.0f, p2 = 0.0f, p3 = 0.0f;
#pragma unroll
        for (int nt2 = 0; nt2 < 8; ++nt2) {
            int c = nt2 * 16 + row16;
            int swzB = (c & 7) << 4;
            half8 bf0 = *(const half8*)((const char*)W1s + c * 128 + ((kg * 16) ^ swzB));
            half8 bf1 = *(const half8*)((const char*)W1s + c * 128 + ((64 + kg * 16) ^ swzB));
            f32x4 acc4 = {0.0f, 0.0f, 0.0f, 0.0f};
            acc4 = __builtin_amdgcn_mfma_f32_16x16x32_f16(a0, bf0, acc4, 0, 0, 0);
            acc4 = __builtin_amdgcn_mfma_f32_16x16x32_f16(a1, bf1, acc4, 0, 0, 0);
            float b1v = b1s[c];
            float w2v = W2s[c];
            float h;
            h = fmaxf(acc4[0] + b1v, 0.0f); p0 = fmaf(h, w2v, p0);
            h = fmaxf(acc4[1] + b1v, 0.0f); p1 = fmaf(h, w2v, p1);
            h = fmaxf(acc4[2] + b1v, 0.0f); p2 = fmaf(h, w2v, p2);
            h = fmaxf(acc4[3] + b1v, 0.0f); p3 = fmaf(h, w2v, p3);
        }
#pragma unroll
        for (int off = 1; off < 16; off <<= 1) {
            p0 += __shfl_xor(p0, off, 64);
            p1 += __shfl_xor(p1, off, 64);
            p2 += __shfl_xor(p2, off, 64);
            p3 += __shfl_xor(p3, off, 64);
        }
        if (row16 == 0) {
            int nd = node0 + wave * 16 + kg * 4;
            if (nd + 0 < n) svs[nd + 0] = dinv[nd + 0] * p0;
            if (nd + 1 < n) svs[nd + 1] = dinv[nd + 1] * p1;
            if (nd + 2 < n) svs[nd + 2] = dinv[nd + 2] * p2;
            if (nd + 3 < n) svs[nd + 3] = dinv[nd + 3] * p3;
        }
    }
}

// 4 nodes per wave: out[d] = dD*(sum svs[src] + svs[d]) + b2
__global__ __launch_bounds__(256) void k_out(const int* __restrict__ rowPtr,
                                             const int* __restrict__ eSrc,
                                             const float* __restrict__ dinv,
                                             const float* __restrict__ svs,
                                             const float* __restrict__ b2,
                                             float* __restrict__ out, int n) {
    int t = blockIdx.x * blockDim.x + threadIdx.x;
    int node = t >> 4;
    int r = t & 15;
    if (node >= n) return;
    int beg = rowPtr[node];
    int end = rowPtr[node + 1];
    float p = 0.0f;
    for (int j = beg + r; j < end; j += 16) p += svs[eSrc[j]];
    p += __shfl_xor(p, 1, 16);
    p += __shfl_xor(p, 2, 16);
    p += __shfl_xor(p, 4, 16);
    p += __shfl_xor(p, 8, 16);
    if (r == 0) {
        float dD = dinv[node];
        out[node] = fmaf(dD, p + svs[node], b2[0]);
    }
}

extern "C" void kernel_launch(void* const* d_in, const int* in_sizes, int n_in,
                              void* d_out, int out_size, void* d_ws, size_t ws_size,
                              hipStream_t stream) {
    const float* X  = (const float*)d_in[0];
    const int*   ei = (const int*)d_in[1];   // int32 (jax x64 disabled)
    const float* W1 = (const float*)d_in[2];
    const float* b1 = (const float*)d_in[3];
    const float* W2 = (const float*)d_in[4];
    const float* b2 = (const float*)d_in[5];

    int N = in_sizes[0] / INF;  // 100000
    int E = in_sizes[1] / 2;    // 1600000
    const int* srcA = ei;
    const int* dstA = ei + E;

    int nt  = (E + TILE_E - 1) / TILE_E;       // 261 tiles
    int nbk = (N + BKSZ - 1) >> BKBITS;        // 391 buckets

    // workspace layout (16B-aligned head first)
    uint4*    Xs4      = (uint4*)d_ws;                     // N*8 = 12.8 MB
    unsigned* binned   = (unsigned*)(Xs4 + (size_t)N * 8); // nt*TILE_E
    int*      eSrc     = (int*)(binned + (size_t)nt * TILE_E);  // E
    _Float16* W1t      = (_Float16*)(eSrc + E);            // HID*INF
    int*      tileOff  = (int*)(W1t + HID * INF);          // nt*(nbk+1)
    int*      rowPtr   = tileOff + nt * (nbk + 1);         // N+1
    float*    dinv     = (float*)(rowPtr + N + 1);         // N
    float*    svs      = dinv + N;                         // N
    float*    out      = (float*)d_out;

    k_histbin<<<nt + 1, 1024, 0, stream>>>(srcA, dstA, tileOff, binned, E, nt, nbk,
                                           W1, W1t);
    k_csr<<<nbk, 512, 0, stream>>>(binned, tileOff, rowPtr, dinv, eSrc,
                                   (const float4*)X, Xs4, N, nt, nbk);
    k_agg_mlp<<<(N + 31) / 32, 256, 0, stream>>>(Xs4, rowPtr, eSrc, dinv,
                                                 (const uint4*)W1t, b1, W2, svs, N);
    k_out<<<(N * 16 + 255) / 256, 256, 0, stream>>>(rowPtr, eSrc, dinv, svs, b2, out, N);
}